// Round 3
// baseline (105.482 us; speedup 1.0000x reference)
//
#include <hip/hip_runtime.h>
#include <math.h>

#define BB 32
#define NN 4096
#define DD 768
#define CC 10
#define KK 16

// ---------------------------------------------------------------------------
// Kernel 1: scores s[b,n] = dot(H[b,n,:], w_score) + b_score
// Persistent-style: 2048 blocks x 4 waves; each wave owns 16 consecutive rows,
// processed 4 at a time. w_score lives in 3 float4 REGISTERS per lane (each
// lane always reads positions {lane, lane+64, lane+128}) -> no LDS, no
// barriers. 12 float4 loads in flight per lane per iteration; one 6-step
// butterfly reduces 4 rows at once; lane 0 stores a float4 of 4 scores.
// ---------------------------------------------------------------------------
__global__ __launch_bounds__(256) void score_kernel(
    const float* __restrict__ H, const float* __restrict__ w,
    const float* __restrict__ b_score, float* __restrict__ s) {
  const int wave_id = blockIdx.x * 4 + (threadIdx.x >> 6);
  const int lane = threadIdx.x & 63;

  const float4* __restrict__ w4 = (const float4*)w;
  const float4 w0 = w4[lane];
  const float4 w1 = w4[lane + 64];
  const float4 w2 = w4[lane + 128];
  const float bs = b_score[0];

  const long row0 = (long)wave_id * 16;          // 16 rows per wave
  const float4* __restrict__ H4 = (const float4*)H;

  for (int it = 0; it < 4; ++it) {               // 4 iterations x 4 rows
    const long r = row0 + it * 4;
    const float4* __restrict__ p = H4 + r * 192; // 192 float4 per row

    float4 h[4][3];
#pragma unroll
    for (int rr = 0; rr < 4; ++rr)
#pragma unroll
      for (int j = 0; j < 3; ++j)
        h[rr][j] = p[rr * 192 + lane + j * 64];

    float acc[4];
#pragma unroll
    for (int rr = 0; rr < 4; ++rr) {
      float a = h[rr][0].x * w0.x + h[rr][0].y * w0.y +
                h[rr][0].z * w0.z + h[rr][0].w * w0.w;
      a += h[rr][1].x * w1.x + h[rr][1].y * w1.y +
           h[rr][1].z * w1.z + h[rr][1].w * w1.w;
      a += h[rr][2].x * w2.x + h[rr][2].y * w2.y +
           h[rr][2].z * w2.z + h[rr][2].w * w2.w;
      acc[rr] = a;
    }

#pragma unroll
    for (int off = 32; off >= 1; off >>= 1) {
#pragma unroll
      for (int rr = 0; rr < 4; ++rr)
        acc[rr] += __shfl_xor(acc[rr], off, 64);
    }

    if (lane == 0) {
      float4 o = {acc[0] + bs, acc[1] + bs, acc[2] + bs, acc[3] + bs};
      ((float4*)s)[r >> 2] = o;
    }
  }
}

// ---------------------------------------------------------------------------
// Kernel 2 (fused tail): per-batch top-16 (register-resident iterative argmax,
// 2 barriers/iter), A one-hot write, and gather+mean+matvec fused (no M[]
// LDS round-trip). One block per batch. Tie-break: smaller index (lax.top_k).
// ---------------------------------------------------------------------------
__global__ __launch_bounds__(256) void tail_kernel(
    const float* __restrict__ s, const float* __restrict__ H,
    const float* __restrict__ Wc, const float* __restrict__ bc,
    float* __restrict__ logits, float* __restrict__ A) {
  const int b = blockIdx.x;
  const int t = threadIdx.x;
  const int wave = t >> 6;
  const int lane = t & 63;

  __shared__ float wv[4];
  __shared__ int wi[4];
  __shared__ int winners[KK];
  __shared__ float wp[4][CC];

  // Each thread owns 16 consecutive scores [t*16, t*16+16) in registers.
  float v[16];
  {
    const float4* sv4 = (const float4*)(s + (long)b * NN);
    float4 a0 = sv4[t * 4 + 0];
    float4 a1 = sv4[t * 4 + 1];
    float4 a2 = sv4[t * 4 + 2];
    float4 a3 = sv4[t * 4 + 3];
    v[0] = a0.x;  v[1] = a0.y;  v[2] = a0.z;  v[3] = a0.w;
    v[4] = a1.x;  v[5] = a1.y;  v[6] = a1.z;  v[7] = a1.w;
    v[8] = a2.x;  v[9] = a2.y;  v[10] = a2.z; v[11] = a2.w;
    v[12] = a3.x; v[13] = a3.y; v[14] = a3.z; v[15] = a3.w;
  }

  // Local running argmax (ascending scan keeps smallest index on ties).
  float lv = v[0];
  int li = t * 16;
#pragma unroll
  for (int j = 1; j < 16; ++j)
    if (v[j] > lv) { lv = v[j]; li = t * 16 + j; }

  for (int k = 0; k < KK; ++k) {
    float rv = lv;
    int ri = li;
#pragma unroll
    for (int off = 1; off < 64; off <<= 1) {
      float ov = __shfl_xor(rv, off, 64);
      int oi = __shfl_xor(ri, off, 64);
      if (ov > rv || (ov == rv && oi < ri)) { rv = ov; ri = oi; }
    }
    if (lane == 0) { wv[wave] = rv; wi[wave] = ri; }
    __syncthreads();

    float bv = wv[0];
    int bi = wi[0];
#pragma unroll
    for (int wq = 1; wq < 4; ++wq) {
      float ov = wv[wq];
      int oi = wi[wq];
      if (ov > bv || (ov == bv && oi < bi)) { bv = ov; bi = oi; }
    }
    if (t == 0) winners[k] = bi;

    if ((bi >> 4) == t) {
      const int slot = bi & 15;
#pragma unroll
      for (int j = 0; j < 16; ++j)
        if (j == slot) v[j] = -INFINITY;
      lv = -INFINITY;
      li = t * 16;
#pragma unroll
      for (int j = 0; j < 16; ++j)
        if (v[j] > lv) { lv = v[j]; li = t * 16 + j; }
    }
    __syncthreads();  // protects wv/wi rewrite; winners[] visible after loop
  }

  // --- A one-hot write: 4096 floats per batch, float4 stores. ---
#pragma unroll
  for (int jj = 0; jj < 4; ++jj) {
    const int q = t + jj * 256;       // float4 index in [0,1024)
    const int n0 = q * 4;
    float4 av = {0.f, 0.f, 0.f, 0.f};
#pragma unroll
    for (int k = 0; k < KK; ++k) {
      int d = winners[k] - n0;
      if (d == 0) av.x = 0.0625f;
      else if (d == 1) av.y = 0.0625f;
      else if (d == 2) av.z = 0.0625f;
      else if (d == 3) av.w = 0.0625f;
    }
    ((float4*)(A + (long)b * NN))[q] = av;
  }

  // --- Gather + mean + matvec fused: part[c] += (sum_k H[..])*(1/16)*Wc ---
  float part[CC];
#pragma unroll
  for (int c = 0; c < CC; ++c) part[c] = 0.f;
  for (int d = t; d < DD; d += 256) {
    float g = 0.f;
#pragma unroll
    for (int k = 0; k < KK; ++k)
      g += H[((long)b * NN + winners[k]) * DD + d];
    g *= (1.f / 16.f);
#pragma unroll
    for (int c = 0; c < CC; ++c) part[c] += g * Wc[d * CC + c];
  }
#pragma unroll
  for (int off = 32; off >= 1; off >>= 1) {
#pragma unroll
    for (int c = 0; c < CC; ++c) part[c] += __shfl_xor(part[c], off, 64);
  }
  if (lane == 0) {
#pragma unroll
    for (int c = 0; c < CC; ++c) wp[wave][c] = part[c];
  }
  __syncthreads();
  if (t < CC) {
    float r = wp[0][t] + wp[1][t] + wp[2][t] + wp[3][t];
    logits[b * CC + t] = r + bc[t];
  }
}

// ---------------------------------------------------------------------------
extern "C" void kernel_launch(void* const* d_in, const int* in_sizes, int n_in,
                              void* d_out, int out_size, void* d_ws, size_t ws_size,
                              hipStream_t stream) {
  const float* H = (const float*)d_in[0];
  const float* w_score = (const float*)d_in[1];
  const float* b_score = (const float*)d_in[2];
  const float* W_cls = (const float*)d_in[3];
  const float* b_cls = (const float*)d_in[4];

  float* out = (float*)d_out;
  float* logits = out;            // [B, C] = 320 floats
  float* A = out + BB * CC;       // [B, N, 1] = 131072 floats

  float* s = (float*)d_ws;        // B*N floats of scratch

  // 131072 rows / 16 rows-per-wave = 8192 waves = 2048 blocks of 4 waves.
  score_kernel<<<2048, 256, 0, stream>>>(H, w_score, b_score, s);
  tail_kernel<<<BB, 256, 0, stream>>>(s, H, W_cls, b_cls, logits, A);
}